// Round 7
// baseline (71.352 us; speedup 1.0000x reference)
//
#include <hip/hip_runtime.h>
#include <cfloat>
#include <cmath>

// x[B,W,L], shapelets[N,L], cls_w[1,N], cls_b[1]
constexpr int B = 64;
constexpr int W = 256;
constexpr int N = 128;
constexpr int L = 64;
constexpr int NC = 16;        // window-chunks per batch element
constexpr int WPB = W / NC;   // 16 windows per block

// Arrival counters, one 128-byte line per b (R5: neutral but sound & free).
// Zero-initialized at module load; last block restores 0 for the next graph
// replay (R2-verified under graph capture + rocprof counter replay).
struct __align__(128) PaddedCnt { int v; int pad[31]; };
__device__ PaddedCnt g_cnt[B];

// VALU-pipe cross-lane add (DPP), avoiding the DS pipe entirely.
// CTRL: 0xB1 = quad_perm xor1, 0x4E = quad_perm xor2,
//       0x141 = row_half_mirror (xor-4 class), 0x140 = row_mirror (xor-8).
template <int CTRL>
__device__ __forceinline__ float dpp_add(float v) {
  return v + __int_as_float(__builtin_amdgcn_update_dpp(
                 0, __float_as_int(v), CTRL, 0xF, 0xF, true));
}

// First 2 products as mul+add (start two FMA-units' worth of work), rest FMA.
#define DOT_INIT(x0, sa) ((x0).x * (sa).x + (x0).y * (sa).y)
#define DOT_TAIL(acc, x0, x1, sa, sb)                      \
  acc = fmaf((x0).z, (sa).z, acc);                         \
  acc = fmaf((x0).w, (sa).w, acc);                         \
  acc = fmaf((x1).x, (sb).x, acc);                         \
  acc = fmaf((x1).y, (sb).y, acc);                         \
  acc = fmaf((x1).z, (sb).z, acc);                         \
  acc = fmaf((x1).w, (sb).w, acc)
// 8-lane sum: 3-stage DPP tree (pure VALU).
#define RED8(v)                                            \
  v = dpp_add<0xB1>(v);                                    \
  v = dpp_add<0x4E>(v);                                    \
  v = dpp_add<0x141>(v)

// ---------------------------------------------------------------------------
// FUSED kernel, round 7. R6 confirmed the exposed-latency theory (4->8 chains
// = -1.55us, best 67.25). This round extends the same lever one notch:
//   (1) FOUR windows per iteration (contiguous wb..wb+3) -> 16 independent
//       dot chains per wave; __launch_bounds__(256,4) pins regalloc to the
//       128-VGPR / 4-blocks-per-CU budget (no occupancy cliff, no R9 spill).
//   (2) xnorm read as ONE ds_read_b128 per iteration (aligned float4[4])
//       instead of 4 scalar ds_read_b32.
//   (3) #pragma unroll on the 4-iter loop so next iter's ds_reads issue
//       under the current DPP trees.
// Hot-loop math, epilogue, arrival protocol frozen (R5/R6-proven).
// Pre-commit: if this gains <1us, the ILP lever is exhausted -> practical
// roofline (fill 41us + gaps ~7us dominate; kernel ~2x droop-adjusted floor).
// grid = B*NC = 1024, block = 256 (4 blocks/CU).
// ---------------------------------------------------------------------------
__global__ __launch_bounds__(256, 4)
void shapelet_fused_kernel(const float* __restrict__ x,
                           const float* __restrict__ shp,
                           const float* __restrict__ cls_w,
                           const float* __restrict__ cls_b,
                           float* __restrict__ part,
                           float* __restrict__ out) {
  __shared__ float xs[WPB * L];    // 4 KB
  __shared__ float4 xnorm4[WPB / 4];  // 16 window norms, float4-aligned
  __shared__ int s_last;
  __shared__ float red[2];

  const int b = blockIdx.x >> 4;
  const int c = blockIdx.x & 15;
  const int tid = threadIdx.x;
  const int oct = tid & 7;        // eighth-of-row owned by this lane
  const int grp = tid >> 3;       // 0..31 -> shapelets 4*grp..4*grp+3
  const int n0 = grp * 4;

  // --- Issue shapelet loads FIRST so their HBM/L2 latency overlaps the
  // x-staging below (8 named float4 = 32 VGPRs, no arrays).
  const float4* g0 = (const float4*)(shp + (size_t)(n0 + 0) * L + oct * 8);
  const float4* g1 = (const float4*)(shp + (size_t)(n0 + 1) * L + oct * 8);
  const float4* g2 = (const float4*)(shp + (size_t)(n0 + 2) * L + oct * 8);
  const float4* g3 = (const float4*)(shp + (size_t)(n0 + 3) * L + oct * 8);
  const float4 s0a = g0[0], s0b = g0[1];
  const float4 s1a = g1[0], s1b = g1[1];
  const float4 s2a = g2[0], s2b = g2[1];
  const float4 s3a = g3[0], s3b = g3[1];

  // --- Stage x[b, c*16:(c+1)*16, :]: one float4/thread; ||x_w||^2 via a
  // 16-lane DPP reduction — zero DS-pipe swizzles.
  {
    const float4* xg =
        (const float4*)(x + ((size_t)b * W + (size_t)c * WPB) * L);
    float4 v = xg[tid];
    ((float4*)xs)[tid] = v;
    float p = v.x * v.x + v.y * v.y + v.z * v.z + v.w * v.w;
    p = dpp_add<0xB1>(p);    // xor1 (quad)
    p = dpp_add<0x4E>(p);    // xor2 (quad)
    p = dpp_add<0x141>(p);   // 4<->8 within row of 16
    p = dpp_add<0x140>(p);   // mirror row of 16
    if ((tid & 15) == 0) ((float*)xnorm4)[tid >> 4] = p;
  }

  __syncthreads();

  // --- min over 16 windows of (xnorm_w - 2*dot(x_w, s_n)), FOUR contiguous
  // windows per iteration: 16 independent accumulation chains per wave.
  float best0 = FLT_MAX, best1 = FLT_MAX, best2 = FLT_MAX, best3 = FLT_MAX;
#pragma unroll
  for (int it = 0; it < WPB / 4; ++it) {
    const float* xw = xs + (size_t)(it * 4) * L + oct * 8;
    const float4 xA0 = *(const float4*)(xw + 0 * L);
    const float4 xA1 = *(const float4*)(xw + 0 * L + 4);
    const float4 xB0 = *(const float4*)(xw + 1 * L);
    const float4 xB1 = *(const float4*)(xw + 1 * L + 4);
    const float4 xC0 = *(const float4*)(xw + 2 * L);
    const float4 xC1 = *(const float4*)(xw + 2 * L + 4);
    const float4 xD0 = *(const float4*)(xw + 3 * L);
    const float4 xD1 = *(const float4*)(xw + 3 * L + 4);
    const float4 xn = xnorm4[it];  // one ds_read_b128, wave-uniform broadcast

    // 16 independent dot chains (4 windows x 4 shapelets).
    float dA0 = DOT_INIT(xA0, s0a), dA1 = DOT_INIT(xA0, s1a);
    float dA2 = DOT_INIT(xA0, s2a), dA3 = DOT_INIT(xA0, s3a);
    float dB0 = DOT_INIT(xB0, s0a), dB1 = DOT_INIT(xB0, s1a);
    float dB2 = DOT_INIT(xB0, s2a), dB3 = DOT_INIT(xB0, s3a);
    float dC0 = DOT_INIT(xC0, s0a), dC1 = DOT_INIT(xC0, s1a);
    float dC2 = DOT_INIT(xC0, s2a), dC3 = DOT_INIT(xC0, s3a);
    float dD0 = DOT_INIT(xD0, s0a), dD1 = DOT_INIT(xD0, s1a);
    float dD2 = DOT_INIT(xD0, s2a), dD3 = DOT_INIT(xD0, s3a);
    DOT_TAIL(dA0, xA0, xA1, s0a, s0b); DOT_TAIL(dA1, xA0, xA1, s1a, s1b);
    DOT_TAIL(dA2, xA0, xA1, s2a, s2b); DOT_TAIL(dA3, xA0, xA1, s3a, s3b);
    DOT_TAIL(dB0, xB0, xB1, s0a, s0b); DOT_TAIL(dB1, xB0, xB1, s1a, s1b);
    DOT_TAIL(dB2, xB0, xB1, s2a, s2b); DOT_TAIL(dB3, xB0, xB1, s3a, s3b);
    DOT_TAIL(dC0, xC0, xC1, s0a, s0b); DOT_TAIL(dC1, xC0, xC1, s1a, s1b);
    DOT_TAIL(dC2, xC0, xC1, s2a, s2b); DOT_TAIL(dC3, xC0, xC1, s3a, s3b);
    DOT_TAIL(dD0, xD0, xD1, s0a, s0b); DOT_TAIL(dD1, xD0, xD1, s1a, s1b);
    DOT_TAIL(dD2, xD0, xD1, s2a, s2b); DOT_TAIL(dD3, xD0, xD1, s3a, s3b);

    // 16 independent 3-stage DPP trees.
    RED8(dA0); RED8(dA1); RED8(dA2); RED8(dA3);
    RED8(dB0); RED8(dB1); RED8(dB2); RED8(dB3);
    RED8(dC0); RED8(dC1); RED8(dC2); RED8(dC3);
    RED8(dD0); RED8(dD1); RED8(dD2); RED8(dD3);

    // min fold (fminf pairs -> v_min3_f32 candidates).
    best0 = fminf(fminf(best0, fmaf(-2.f, dA0, xn.x)),
                  fmaf(-2.f, dB0, xn.y));
    best0 = fminf(fminf(best0, fmaf(-2.f, dC0, xn.z)),
                  fmaf(-2.f, dD0, xn.w));
    best1 = fminf(fminf(best1, fmaf(-2.f, dA1, xn.x)),
                  fmaf(-2.f, dB1, xn.y));
    best1 = fminf(fminf(best1, fmaf(-2.f, dC1, xn.z)),
                  fmaf(-2.f, dD1, xn.w));
    best2 = fminf(fminf(best2, fmaf(-2.f, dA2, xn.x)),
                  fmaf(-2.f, dB2, xn.y));
    best2 = fminf(fminf(best2, fmaf(-2.f, dC2, xn.z)),
                  fmaf(-2.f, dD2, xn.w));
    best3 = fminf(fminf(best3, fmaf(-2.f, dA3, xn.x)),
                  fmaf(-2.f, dB3, xn.y));
    best3 = fminf(fminf(best3, fmaf(-2.f, dC3, xn.z)),
                  fmaf(-2.f, dD3, xn.w));
  }

  // --- oct-leader writes 4 chunk-mins (xnorm - 2dot; ||s||^2 added in tail)
  // as AGENT-scope (sc1) write-through stores: cross-XCD visible with no
  // cache-maintenance instructions (R2-verified protocol).
  if (oct == 0) {
    float* p = part + ((size_t)b * NC + c) * N + n0;
    __hip_atomic_store(p + 0, best0, __ATOMIC_RELAXED,
                       __HIP_MEMORY_SCOPE_AGENT);
    __hip_atomic_store(p + 1, best1, __ATOMIC_RELAXED,
                       __HIP_MEMORY_SCOPE_AGENT);
    __hip_atomic_store(p + 2, best2, __ATOMIC_RELAXED,
                       __HIP_MEMORY_SCOPE_AGENT);
    __hip_atomic_store(p + 3, best3, __ATOMIC_RELAXED,
                       __HIP_MEMORY_SCOPE_AGENT);
  }

  // --- Arrival (R2 protocol): __syncthreads() emits s_waitcnt vmcnt(0) in
  // every wave, so all sc1 part-stores are at the agent-coherent point before
  // tid0's relaxed agent arrival add. One atomic per block, private line.
  __syncthreads();
  if (tid == 0) {
    int done = __hip_atomic_fetch_add(&g_cnt[b].v, 1, __ATOMIC_RELAXED,
                                      __HIP_MEMORY_SCOPE_AGENT);
    s_last = (done == NC - 1) ? 1 : 0;
    if (done == NC - 1)
      __hip_atomic_store(&g_cnt[b].v, 0, __ATOMIC_RELAXED,
                         __HIP_MEMORY_SCOPE_AGENT);  // clean for next replay
  }
  __syncthreads();
  if (!s_last) return;

  // --- Last block for this b: classifier head (min over chunks + ||s_n||^2
  // + sqrt + dot + sigmoid). All 256 threads alive (uniform branch on shared
  // s_last) so the barrier below is safe. part reads are agent-scope loads
  // (bypass stale L1/L2); for fixed cc, lanes read consecutive n -> coalesced.
  float v = 0.f;
  if (tid < N) {
    const float* pb = part + (size_t)b * NC * N + tid;
    float m = FLT_MAX;
#pragma unroll
    for (int cc = 0; cc < NC; ++cc) {
      float pv = __hip_atomic_load(pb + cc * N, __ATOMIC_RELAXED,
                                   __HIP_MEMORY_SCOPE_AGENT);
      m = fminf(m, pv);
    }
    // ||s_n||^2 once per b (shp is L2-hot; read-only data, plain loads).
    float sn = 0.f;
    const float4* sg = (const float4*)(shp + (size_t)tid * L);
#pragma unroll
    for (int i = 0; i < L / 4; ++i) {
      float4 s = sg[i];
      sn = fmaf(s.x, s.x, sn);
      sn = fmaf(s.y, s.y, sn);
      sn = fmaf(s.z, s.z, sn);
      sn = fmaf(s.w, s.w, sn);
    }
    float d2 = fmaxf(m + sn, 0.f);  // guard fp rounding before sqrt
    v = sqrtf(d2) * cls_w[tid];
  }
#pragma unroll
  for (int off = 32; off > 0; off >>= 1) v += __shfl_down(v, off, 64);
  if ((tid & 63) == 0) red[tid >> 6] = v;
  __syncthreads();
  if (tid == 0) {
    float z = red[0] + red[1] + cls_b[0];
    out[b] = 1.0f / (1.0f + expf(-z));
  }
}

extern "C" void kernel_launch(void* const* d_in, const int* in_sizes, int n_in,
                              void* d_out, int out_size, void* d_ws,
                              size_t ws_size, hipStream_t stream) {
  const float* x = (const float*)d_in[0];      // [B, W, L]
  const float* shp = (const float*)d_in[1];    // [N, L]
  const float* cls_w = (const float*)d_in[2];  // [1, N]
  const float* cls_b = (const float*)d_in[3];  // [1]
  float* out = (float*)d_out;                  // [B, 1]
  float* part = (float*)d_ws;                  // [B, NC, N] fp32 (512 KB)

  shapelet_fused_kernel<<<B * NC, 256, 0, stream>>>(x, shp, cls_w, cls_b,
                                                    part, out);
}

// Round 8
// 68.774 us; speedup vs baseline: 1.0375x; 1.0375x over previous
//
#include <hip/hip_runtime.h>
#include <cfloat>
#include <cmath>

// x[B,W,L], shapelets[N,L], cls_w[1,N], cls_b[1]
constexpr int B = 64;
constexpr int W = 256;
constexpr int N = 128;
constexpr int L = 64;
constexpr int NC = 16;        // window-chunks per batch element
constexpr int WPB = W / NC;   // 16 windows per block

// Arrival counters, one 128-byte line per b (R5: neutral vs shared lines,
// kept because it is sound and free). Zero-initialized at module load; last
// block restores 0 for the next graph replay (R2-verified under graph
// capture + rocprof counter replay).
struct __align__(128) PaddedCnt { int v; int pad[31]; };
__device__ PaddedCnt g_cnt[B];

// VALU-pipe cross-lane add (DPP), avoiding the DS pipe entirely.
// CTRL: 0xB1 = quad_perm xor1, 0x4E = quad_perm xor2,
//       0x141 = row_half_mirror (xor-4 class), 0x140 = row_mirror (xor-8).
template <int CTRL>
__device__ __forceinline__ float dpp_add(float v) {
  return v + __int_as_float(__builtin_amdgcn_update_dpp(
                 0, __float_as_int(v), CTRL, 0xF, 0xF, true));
}

// ---------------------------------------------------------------------------
// FUSED kernel — FINAL = R6, the measured optimum of the ILP scan:
//   4 chains (R2/R5) -> 68.8us | 8 chains (R6) -> 67.25us | 16 (R7) -> 71.4us
// R7's 16-chain version hit the 128-VGPR wall (live x-data + shapelets +
// accumulators ~120+) and regressed; 8 chains at ~80 VGPR is the knee.
//
// Structure: 2 windows per iteration (w and w+8) -> 8 independent dot chains
// per wave; shapelet loads issued before x-staging; R2-verified sc1-store +
// relaxed-agent-atomic arrival protocol; last block runs the classifier head.
// Session ledger: fill 41us + gaps ~7us are harness-fixed (72% of dur);
// kernel ~19us vs ~9us ideal-clock issue arithmetic (clock droop behind the
// 6.6TB/s fill + flattened latency curve). All structural alternatives
// (two-kernel, per-wave arrival, 2x occupancy, counter padding, 16-chain)
// measured >= this.
// grid = B*NC = 1024, block = 256 (4 blocks/CU).
// ---------------------------------------------------------------------------
__global__ __launch_bounds__(256)
void shapelet_fused_kernel(const float* __restrict__ x,
                           const float* __restrict__ shp,
                           const float* __restrict__ cls_w,
                           const float* __restrict__ cls_b,
                           float* __restrict__ part,
                           float* __restrict__ out) {
  __shared__ float xs[WPB * L];   // 4 KB
  __shared__ float xnorm_s[WPB];
  __shared__ int s_last;
  __shared__ float red[2];

  const int b = blockIdx.x >> 4;
  const int c = blockIdx.x & 15;
  const int tid = threadIdx.x;
  const int oct = tid & 7;        // eighth-of-row owned by this lane
  const int grp = tid >> 3;       // 0..31 -> shapelets 4*grp..4*grp+3
  const int n0 = grp * 4;

  // --- Issue shapelet loads FIRST so their HBM/L2 latency overlaps the
  // x-staging below (8 named float4 = 32 VGPRs, no arrays).
  const float4* g0 = (const float4*)(shp + (size_t)(n0 + 0) * L + oct * 8);
  const float4* g1 = (const float4*)(shp + (size_t)(n0 + 1) * L + oct * 8);
  const float4* g2 = (const float4*)(shp + (size_t)(n0 + 2) * L + oct * 8);
  const float4* g3 = (const float4*)(shp + (size_t)(n0 + 3) * L + oct * 8);
  const float4 s0a = g0[0], s0b = g0[1];
  const float4 s1a = g1[0], s1b = g1[1];
  const float4 s2a = g2[0], s2b = g2[1];
  const float4 s3a = g3[0], s3b = g3[1];

  // --- Stage x[b, c*16:(c+1)*16, :]: one float4/thread; ||x_w||^2 via a
  // 16-lane DPP reduction — zero DS-pipe swizzles.
  {
    const float4* xg =
        (const float4*)(x + ((size_t)b * W + (size_t)c * WPB) * L);
    float4 v = xg[tid];
    ((float4*)xs)[tid] = v;
    float p = v.x * v.x + v.y * v.y + v.z * v.z + v.w * v.w;
    p = dpp_add<0xB1>(p);    // xor1 (quad)
    p = dpp_add<0x4E>(p);    // xor2 (quad)
    p = dpp_add<0x141>(p);   // 4<->8 within row of 16
    p = dpp_add<0x140>(p);   // mirror row of 16
    if ((tid & 15) == 0) xnorm_s[tid >> 4] = p;
  }

  __syncthreads();

  // --- min over 16 windows of (xnorm_w - 2*dot(x_w, s_n)), TWO windows per
  // iteration (w and w+8): 8 independent accumulation chains per wave.
  float best0 = FLT_MAX, best1 = FLT_MAX, best2 = FLT_MAX, best3 = FLT_MAX;
  for (int w = 0; w < WPB / 2; ++w) {
    const float4* xr0 = (const float4*)(xs + (size_t)w * L + oct * 8);
    const float4* xr1 = (const float4*)(xs + (size_t)(w + 8) * L + oct * 8);
    const float4 xa = xr0[0];
    const float4 xb = xr0[1];
    const float4 ya = xr1[0];
    const float4 yb = xr1[1];

    // Window w -> d0..d3
    float d0 = xa.x * s0a.x + xa.y * s0a.y;
    float d1 = xa.x * s1a.x + xa.y * s1a.y;
    float d2 = xa.x * s2a.x + xa.y * s2a.y;
    float d3 = xa.x * s3a.x + xa.y * s3a.y;
    // Window w+8 -> e0..e3 (independent chains, interleaved by the compiler)
    float e0 = ya.x * s0a.x + ya.y * s0a.y;
    float e1 = ya.x * s1a.x + ya.y * s1a.y;
    float e2 = ya.x * s2a.x + ya.y * s2a.y;
    float e3 = ya.x * s3a.x + ya.y * s3a.y;

    d0 = fmaf(xa.z, s0a.z, d0); d0 = fmaf(xa.w, s0a.w, d0);
    d1 = fmaf(xa.z, s1a.z, d1); d1 = fmaf(xa.w, s1a.w, d1);
    d2 = fmaf(xa.z, s2a.z, d2); d2 = fmaf(xa.w, s2a.w, d2);
    d3 = fmaf(xa.z, s3a.z, d3); d3 = fmaf(xa.w, s3a.w, d3);
    e0 = fmaf(ya.z, s0a.z, e0); e0 = fmaf(ya.w, s0a.w, e0);
    e1 = fmaf(ya.z, s1a.z, e1); e1 = fmaf(ya.w, s1a.w, e1);
    e2 = fmaf(ya.z, s2a.z, e2); e2 = fmaf(ya.w, s2a.w, e2);
    e3 = fmaf(ya.z, s3a.z, e3); e3 = fmaf(ya.w, s3a.w, e3);

    d0 = fmaf(xb.x, s0b.x, d0); d0 = fmaf(xb.y, s0b.y, d0);
    d1 = fmaf(xb.x, s1b.x, d1); d1 = fmaf(xb.y, s1b.y, d1);
    d2 = fmaf(xb.x, s2b.x, d2); d2 = fmaf(xb.y, s2b.y, d2);
    d3 = fmaf(xb.x, s3b.x, d3); d3 = fmaf(xb.y, s3b.y, d3);
    e0 = fmaf(yb.x, s0b.x, e0); e0 = fmaf(yb.y, s0b.y, e0);
    e1 = fmaf(yb.x, s1b.x, e1); e1 = fmaf(yb.y, s1b.y, e1);
    e2 = fmaf(yb.x, s2b.x, e2); e2 = fmaf(yb.y, s2b.y, e2);
    e3 = fmaf(yb.x, s3b.x, e3); e3 = fmaf(yb.y, s3b.y, e3);

    d0 = fmaf(xb.z, s0b.z, d0); d0 = fmaf(xb.w, s0b.w, d0);
    d1 = fmaf(xb.z, s1b.z, d1); d1 = fmaf(xb.w, s1b.w, d1);
    d2 = fmaf(xb.z, s2b.z, d2); d2 = fmaf(xb.w, s2b.w, d2);
    d3 = fmaf(xb.z, s3b.z, d3); d3 = fmaf(xb.w, s3b.w, d3);
    e0 = fmaf(yb.z, s0b.z, e0); e0 = fmaf(yb.w, s0b.w, e0);
    e1 = fmaf(yb.z, s1b.z, e1); e1 = fmaf(yb.w, s1b.w, e1);
    e2 = fmaf(yb.z, s2b.z, e2); e2 = fmaf(yb.w, s2b.w, e2);
    e3 = fmaf(yb.z, s3b.z, e3); e3 = fmaf(yb.w, s3b.w, e3);

    // 8-lane reductions — 8 independent 3-stage DPP trees.
    d0 = dpp_add<0xB1>(d0);  d1 = dpp_add<0xB1>(d1);
    d2 = dpp_add<0xB1>(d2);  d3 = dpp_add<0xB1>(d3);
    e0 = dpp_add<0xB1>(e0);  e1 = dpp_add<0xB1>(e1);
    e2 = dpp_add<0xB1>(e2);  e3 = dpp_add<0xB1>(e3);
    d0 = dpp_add<0x4E>(d0);  d1 = dpp_add<0x4E>(d1);
    d2 = dpp_add<0x4E>(d2);  d3 = dpp_add<0x4E>(d3);
    e0 = dpp_add<0x4E>(e0);  e1 = dpp_add<0x4E>(e1);
    e2 = dpp_add<0x4E>(e2);  e3 = dpp_add<0x4E>(e3);
    d0 = dpp_add<0x141>(d0); d1 = dpp_add<0x141>(d1);
    d2 = dpp_add<0x141>(d2); d3 = dpp_add<0x141>(d3);
    e0 = dpp_add<0x141>(e0); e1 = dpp_add<0x141>(e1);
    e2 = dpp_add<0x141>(e2); e3 = dpp_add<0x141>(e3);

    const float xn0 = xnorm_s[w];
    const float xn1 = xnorm_s[w + 8];
    // fminf(fminf(a,b),c) -> v_min3_f32 candidates for the compiler.
    best0 = fminf(fminf(best0, fmaf(-2.f, d0, xn0)), fmaf(-2.f, e0, xn1));
    best1 = fminf(fminf(best1, fmaf(-2.f, d1, xn0)), fmaf(-2.f, e1, xn1));
    best2 = fminf(fminf(best2, fmaf(-2.f, d2, xn0)), fmaf(-2.f, e2, xn1));
    best3 = fminf(fminf(best3, fmaf(-2.f, d3, xn0)), fmaf(-2.f, e3, xn1));
  }

  // --- oct-leader writes 4 chunk-mins (xnorm - 2dot; ||s||^2 added in tail)
  // as AGENT-scope (sc1) write-through stores: cross-XCD visible with no
  // cache-maintenance instructions (R2-verified protocol).
  if (oct == 0) {
    float* p = part + ((size_t)b * NC + c) * N + n0;
    __hip_atomic_store(p + 0, best0, __ATOMIC_RELAXED,
                       __HIP_MEMORY_SCOPE_AGENT);
    __hip_atomic_store(p + 1, best1, __ATOMIC_RELAXED,
                       __HIP_MEMORY_SCOPE_AGENT);
    __hip_atomic_store(p + 2, best2, __ATOMIC_RELAXED,
                       __HIP_MEMORY_SCOPE_AGENT);
    __hip_atomic_store(p + 3, best3, __ATOMIC_RELAXED,
                       __HIP_MEMORY_SCOPE_AGENT);
  }

  // --- Arrival (R2 protocol): __syncthreads() emits s_waitcnt vmcnt(0) in
  // every wave, so all sc1 part-stores are at the agent-coherent point before
  // tid0's relaxed agent arrival add. One atomic per block, private line.
  __syncthreads();
  if (tid == 0) {
    int done = __hip_atomic_fetch_add(&g_cnt[b].v, 1, __ATOMIC_RELAXED,
                                      __HIP_MEMORY_SCOPE_AGENT);
    s_last = (done == NC - 1) ? 1 : 0;
    if (done == NC - 1)
      __hip_atomic_store(&g_cnt[b].v, 0, __ATOMIC_RELAXED,
                         __HIP_MEMORY_SCOPE_AGENT);  // clean for next replay
  }
  __syncthreads();
  if (!s_last) return;

  // --- Last block for this b: classifier head (min over chunks + ||s_n||^2
  // + sqrt + dot + sigmoid). All 256 threads alive (uniform branch on shared
  // s_last) so the barrier below is safe. part reads are agent-scope loads
  // (bypass stale L1/L2); for fixed cc, lanes read consecutive n ->
  // coalesced.
  float v = 0.f;
  if (tid < N) {
    const float* pb = part + (size_t)b * NC * N + tid;
    float m = FLT_MAX;
#pragma unroll
    for (int cc = 0; cc < NC; ++cc) {
      float pv = __hip_atomic_load(pb + cc * N, __ATOMIC_RELAXED,
                                   __HIP_MEMORY_SCOPE_AGENT);
      m = fminf(m, pv);
    }
    // ||s_n||^2 once per b (shp is L2-hot; read-only data, plain loads).
    float sn = 0.f;
    const float4* sg = (const float4*)(shp + (size_t)tid * L);
#pragma unroll
    for (int i = 0; i < L / 4; ++i) {
      float4 s = sg[i];
      sn = fmaf(s.x, s.x, sn);
      sn = fmaf(s.y, s.y, sn);
      sn = fmaf(s.z, s.z, sn);
      sn = fmaf(s.w, s.w, sn);
    }
    float d2 = fmaxf(m + sn, 0.f);  // guard fp rounding before sqrt
    v = sqrtf(d2) * cls_w[tid];
  }
#pragma unroll
  for (int off = 32; off > 0; off >>= 1) v += __shfl_down(v, off, 64);
  if ((tid & 63) == 0) red[tid >> 6] = v;
  __syncthreads();
  if (tid == 0) {
    float z = red[0] + red[1] + cls_b[0];
    out[b] = 1.0f / (1.0f + expf(-z));
  }
}

extern "C" void kernel_launch(void* const* d_in, const int* in_sizes, int n_in,
                              void* d_out, int out_size, void* d_ws,
                              size_t ws_size, hipStream_t stream) {
  const float* x = (const float*)d_in[0];      // [B, W, L]
  const float* shp = (const float*)d_in[1];    // [N, L]
  const float* cls_w = (const float*)d_in[2];  // [1, N]
  const float* cls_b = (const float*)d_in[3];  // [1]
  float* out = (float*)d_out;                  // [B, 1]
  float* part = (float*)d_ws;                  // [B, NC, N] fp32 (512 KB)

  shapelet_fused_kernel<<<B * NC, 256, 0, stream>>>(x, shp, cls_w, cls_b,
                                                    part, out);
}